// Round 8
// baseline (235.495 us; speedup 1.0000x reference)
//
#include <hip/hip_runtime.h>
#include <math.h>

#define NEGS 0.2f
#define EPSF 1e-5f

typedef short s16x8 __attribute__((ext_vector_type(8)));
typedef float f32x4 __attribute__((ext_vector_type(4)));

__device__ __forceinline__ float b2f(unsigned short u) {
  union { unsigned int i; float f; } v; v.i = ((unsigned int)u) << 16; return v.f;
}
__device__ __forceinline__ unsigned short f2b(float f) {
  union { float f; unsigned int i; } v; v.f = f;
  unsigned int x = v.i;
  return (unsigned short)((x + 0x7fffu + ((x >> 16) & 1u)) >> 16);
}
// fast ELU negative branch: exp(x)-1 via hw exp; |err| ~1e-7 << bf16 tolerance
__device__ __forceinline__ float elu_neg(float x) { return __expf(x) - 1.f; }

// One-shot group barrier among 128 same-XCD blocks. slot = 128 ints (512B):
// 4 sub-counters at slot[0/16/32/48], master at slot[64], flag at slot[96].
// All arrival RMWs RELAXED (producer data already drained to the XCD-shared
// L2 by __syncthreads' vmcnt(0)); the ONLY release is the closing block's
// flag store. Pollers spin RELAXED (zero cache maintenance). Bounded spin.
__device__ __forceinline__ void gbar(int* slot, int sub) {
  __syncthreads();
  if (threadIdx.x == 0) {
    int old = __hip_atomic_fetch_add(slot + sub*16, 1, __ATOMIC_RELAXED, __HIP_MEMORY_SCOPE_AGENT);
    if (old == 31) {
      int om = __hip_atomic_fetch_add(slot + 64, 1, __ATOMIC_RELAXED, __HIP_MEMORY_SCOPE_AGENT);
      if (om == 3)
        __hip_atomic_store(slot + 96, 1, __ATOMIC_RELEASE, __HIP_MEMORY_SCOPE_AGENT);
    }
    int it = 0;
    while (__hip_atomic_load(slot + 96, __ATOMIC_RELAXED, __HIP_MEMORY_SCOPE_AGENT) == 0) {
      __builtin_amdgcn_s_sleep(2);
      if (++it > (1 << 22)) break;
    }
  }
  __syncthreads();
}

// ============ mega kernel, template-truncated for phase attribution ============
// NPH=3: full (F0 -> A0F1 -> A1P -> A2a)   [the real compute path]
// NPH=2: F0 -> A0F1 only                   [probe]
// NPH=1: F0 only                           [probe]
// Probes re-run after k_fin on the same buffers (output already produced).
template<int NPH>
__global__ __launch_bounds__(256, 4) void k_mega(
    const float* __restrict__ inp, const int* __restrict__ src,
    const float* __restrict__ W0, const float* __restrict__ al0, const float* __restrict__ ar0,
    const float* __restrict__ W1, const float* __restrict__ al1, const float* __restrict__ ar1,
    const float* __restrict__ W2, const float* __restrict__ al2, const float* __restrict__ ar2,
    const float* __restrict__ Wr2, const float* __restrict__ tc1w,
    unsigned short* __restrict__ W1bX, unsigned short* __restrict__ feat0,
    unsigned short* __restrict__ feat1,
    float* __restrict__ el0, float* __restrict__ er0,
    float* __restrict__ el1, float* __restrict__ er1,
    float* __restrict__ feat2, float* __restrict__ res2,
    float* __restrict__ x1, int* bar)
{
  __shared__ __align__(16) char pool[22528];
  // persistent src slot [21248, 22272): untouched by any phase's buffers
  int (*ssm)[8] = (int(*)[8])(pool + 21248);
  const int tid = threadIdx.x;
  const int bid = blockIdx.x;
  const int g     = bid & 7;                  // XCD group
  const int bt    = g*4 + ((bid >> 3) & 3);   // XCD-aligned bt slice
  const int nBase = (bid >> 5) * 32;          // 32-node chunk
  const int sub   = (bid >> 3) & 3;           // barrier sub-counter
  const int b = bt >> 3, t = bt & 7;
  const int w = tid >> 6, lane = tid & 63, n16 = lane & 15, q = lane >> 4;

  s16x8 h1r[2][2];   // register-resident h1 slice: [p2][A/B]

  // ---------------- Phase F0: feat0 = (inp^T) @ W0^T ----------------
  {
    unsigned short (*At)[72] = (unsigned short(*)[72])pool;       // 4608 B
    unsigned short *Lb = (unsigned short*)(pool + 4608);          // 16384 B
    ((int*)ssm)[tid] = src[nBase*8 + tid];    // persistent: used by all phases
    s16x8 bf[2][4];
    #pragma unroll
    for (int kc = 0; kc < 2; ++kc)
      #pragma unroll
      for (int ct = 0; ct < 4; ++ct) {
        const float* p = &W0[(size_t)((w*4 + ct)*16 + n16)*64 + kc*32 + q*8];
        float4 wa = *(const float4*)p;
        float4 wb = *(const float4*)(p + 4);
        s16x8 o;
        o[0]=(short)f2b(wa.x); o[1]=(short)f2b(wa.y); o[2]=(short)f2b(wa.z); o[3]=(short)f2b(wa.w);
        o[4]=(short)f2b(wb.x); o[5]=(short)f2b(wb.y); o[6]=(short)f2b(wb.z); o[7]=(short)f2b(wb.w);
        bf[kc][ct] = o;
      }
    {
      const int nn = tid & 7, cg = tid >> 3;    // 8 node-quads x 32 ch-slots
      #pragma unroll
      for (int c2 = 0; c2 < 2; ++c2) {
        const int ch = cg + c2*32;
        float4 v = *(const float4*)&inp[((size_t)(b*64 + ch)*8 + t)*1024 + nBase + nn*4];
        At[nn*4 + 0][ch] = f2b(v.x);
        At[nn*4 + 1][ch] = f2b(v.y);
        At[nn*4 + 2][ch] = f2b(v.z);
        At[nn*4 + 3][ch] = f2b(v.w);
      }
    }
    __syncthreads();
    f32x4 acc[2][4];
    #pragma unroll
    for (int rt = 0; rt < 2; ++rt)
      #pragma unroll
      for (int ct = 0; ct < 4; ++ct) acc[rt][ct] = (f32x4){0.f,0.f,0.f,0.f};
    #pragma unroll
    for (int kc = 0; kc < 2; ++kc) {
      s16x8 af[2];
      #pragma unroll
      for (int rt = 0; rt < 2; ++rt)
        af[rt] = *(const s16x8*)&At[rt*16 + n16][kc*32 + q*8];
      #pragma unroll
      for (int rt = 0; rt < 2; ++rt)
        #pragma unroll
        for (int ct = 0; ct < 4; ++ct)
          acc[rt][ct] = __builtin_amdgcn_mfma_f32_16x16x32_bf16(af[rt], bf[kc][ct], acc[rt][ct], 0, 0, 0);
    }
    float alv[4], arv[4];
    #pragma unroll
    for (int ct = 0; ct < 4; ++ct) {
      alv[ct] = al0[w*64 + ct*16 + n16];
      arv[ct] = ar0[w*64 + ct*16 + n16];
    }
    #pragma unroll
    for (int rt = 0; rt < 2; ++rt) {
      #pragma unroll
      for (int reg = 0; reg < 4; ++reg) {
        float pl = acc[rt][0][reg]*alv[0] + acc[rt][1][reg]*alv[1]
                 + acc[rt][2][reg]*alv[2] + acc[rt][3][reg]*alv[3];
        float pr = acc[rt][0][reg]*arv[0] + acc[rt][1][reg]*arv[1]
                 + acc[rt][2][reg]*arv[2] + acc[rt][3][reg]*arv[3];
        #pragma unroll
        for (int o = 1; o < 16; o <<= 1) { pl += __shfl_xor(pl, o); pr += __shfl_xor(pr, o); }
        if (n16 == 0) {
          int r = (nBase + rt*16 + q*4 + reg)*32 + bt;
          el0[r*4 + w] = pl;
          er0[r*4 + w] = pr;
        }
      }
    }
    #pragma unroll
    for (int rt = 0; rt < 2; ++rt)
      #pragma unroll
      for (int ct = 0; ct < 4; ++ct)
        #pragma unroll
        for (int reg = 0; reg < 4; ++reg)
          Lb[(rt*16 + q*4 + reg)*256 + w*64 + ct*16 + n16] = f2b(acc[rt][ct][reg]);
    __syncthreads();
    #pragma unroll
    for (int i = 0; i < 4; ++i) {
      int u = tid + i*256;
      int m = u >> 5, off = (u & 31) * 8;
      *(s16x8*)&feat0[(size_t)((nBase + m)*32 + bt)*256 + off] = *(const s16x8*)&Lb[m*256 + off];
    }
    // per-XCD W1 -> bf16 copy (each group converts its own copy; stays in its L2)
    if (tid < 128) {
      const int j = ((bid >> 3) << 9) + tid*4;   // 128 blocks/group * 512 = 65536
      float4 w4 = *(const float4*)&W1[j];
      ushort4 o4; o4.x=f2b(w4.x); o4.y=f2b(w4.y); o4.z=f2b(w4.z); o4.w=f2b(w4.w);
      *(ushort4*)&W1bX[(size_t)g*65536 + j] = o4;
    }
  }
  gbar(bar + (0*8 + g)*128, sub);

  // ---------------- Phase A0F1: agg0 + feat1 ----------------
  if constexpr (NPH >= 2) {
    float (*wsm)[8][4] = (float(*)[8][4])pool;                    // 4096 B
    unsigned short *smbuf = (unsigned short*)(pool + 4096);       // 16896 B
    unsigned short (*At)[264] = (unsigned short(*)[264])smbuf;
    unsigned short *Lb = smbuf;
    const int hw2 = tid >> 5, l5 = tid & 31;
    const int c0 = l5 * 8, hh = l5 >> 3;
    s16x8 vA[8], vB[8];
    #pragma unroll
    for (int j = 0; j < 8; ++j) {
      vA[j] = *(const s16x8*)&feat0[(size_t)(ssm[hw2    ][j]*32 + bt)*256 + c0];
      vB[j] = *(const s16x8*)&feat0[(size_t)(ssm[hw2 + 8][j]*32 + bt)*256 + c0];
    }
    if (tid < 128) {
      const int nl = tid >> 2, h = tid & 3;
      const int rn = (nBase + nl)*32 + bt;
      const float erv = er0[rn*4 + h];
      float e[8]; float mx = -1e30f;
      #pragma unroll
      for (int j = 0; j < 8; ++j) {
        float v = el0[(ssm[nl][j]*32 + bt)*4 + h] + erv;
        v = v >= 0.f ? v : NEGS * v;
        e[j] = v; mx = fmaxf(mx, v);
      }
      float den = 0.f;
      #pragma unroll
      for (int j = 0; j < 8; ++j) { e[j] = __expf(e[j] - mx); den += e[j]; }
      const float inv = 1.f / den;
      #pragma unroll
      for (int j = 0; j < 8; ++j) wsm[nl][j][h] = e[j] * inv;
    }
    __syncthreads();
    #pragma unroll
    for (int p2 = 0; p2 < 2; ++p2) {
      const int nlA = p2*16 + hw2, nlB = nlA + 8;
      if (p2 == 1) {
        #pragma unroll
        for (int j = 0; j < 8; ++j) {
          vA[j] = *(const s16x8*)&feat0[(size_t)(ssm[nlA][j]*32 + bt)*256 + c0];
          vB[j] = *(const s16x8*)&feat0[(size_t)(ssm[nlB][j]*32 + bt)*256 + c0];
        }
      }
      asm volatile("" ::: "memory");
      float aA[8] = {0,0,0,0,0,0,0,0}, aB[8] = {0,0,0,0,0,0,0,0};
      #pragma unroll
      for (int j = 0; j < 8; ++j) {
        const float wA = wsm[nlA][j][hh], wB = wsm[nlB][j][hh];
        #pragma unroll
        for (int i = 0; i < 8; ++i) {
          aA[i] = fmaf(wA, b2f((unsigned short)vA[j][i]), aA[i]);
          aB[i] = fmaf(wB, b2f((unsigned short)vB[j][i]), aB[i]);
        }
      }
      s16x8 oA, oB;
      #pragma unroll
      for (int i = 0; i < 8; ++i) {
        float xA = aA[i] > 0.f ? aA[i] : elu_neg(aA[i]);
        float xB = aB[i] > 0.f ? aB[i] : elu_neg(aB[i]);
        oA[i] = (short)f2b(xA); oB[i] = (short)f2b(xB);
      }
      *(s16x8*)&At[nlA][c0] = oA;
      *(s16x8*)&At[nlB][c0] = oB;
      h1r[p2][0] = oA;            // registers, consumed in A1P by this thread
      h1r[p2][1] = oB;
    }
    __syncthreads();
    f32x4 acc[2][4];
    #pragma unroll
    for (int rt = 0; rt < 2; ++rt)
      #pragma unroll
      for (int ct = 0; ct < 4; ++ct) acc[rt][ct] = (f32x4){0.f,0.f,0.f,0.f};
    const unsigned short* W1g = W1bX + (size_t)g*65536;
    #pragma unroll
    for (int kc = 0; kc < 8; ++kc) {
      s16x8 af[2], bfr[4];
      #pragma unroll
      for (int rt = 0; rt < 2; ++rt)
        af[rt] = *(const s16x8*)&At[rt*16 + n16][kc*32 + q*8];
      #pragma unroll
      for (int ct = 0; ct < 4; ++ct)
        bfr[ct] = *(const s16x8*)&W1g[(size_t)((w*4 + ct)*16 + n16)*256 + kc*32 + q*8];
      #pragma unroll
      for (int rt = 0; rt < 2; ++rt)
        #pragma unroll
        for (int ct = 0; ct < 4; ++ct)
          acc[rt][ct] = __builtin_amdgcn_mfma_f32_16x16x32_bf16(af[rt], bfr[ct], acc[rt][ct], 0, 0, 0);
    }
    float alv[4], arv[4];
    #pragma unroll
    for (int ct = 0; ct < 4; ++ct) {
      alv[ct] = al1[w*64 + ct*16 + n16];
      arv[ct] = ar1[w*64 + ct*16 + n16];
    }
    #pragma unroll
    for (int rt = 0; rt < 2; ++rt) {
      #pragma unroll
      for (int reg = 0; reg < 4; ++reg) {
        float pl = acc[rt][0][reg]*alv[0] + acc[rt][1][reg]*alv[1]
                 + acc[rt][2][reg]*alv[2] + acc[rt][3][reg]*alv[3];
        float pr = acc[rt][0][reg]*arv[0] + acc[rt][1][reg]*arv[1]
                 + acc[rt][2][reg]*arv[2] + acc[rt][3][reg]*arv[3];
        #pragma unroll
        for (int o = 1; o < 16; o <<= 1) { pl += __shfl_xor(pl, o); pr += __shfl_xor(pr, o); }
        if (n16 == 0) {
          int r = (nBase + rt*16 + q*4 + reg)*32 + bt;
          el1[r*4 + w] = pl;
          er1[r*4 + w] = pr;
        }
      }
    }
    __syncthreads();   // At aliases Lb: all At reads must finish first
    #pragma unroll
    for (int rt = 0; rt < 2; ++rt)
      #pragma unroll
      for (int ct = 0; ct < 4; ++ct)
        #pragma unroll
        for (int reg = 0; reg < 4; ++reg)
          Lb[(rt*16 + q*4 + reg)*256 + w*64 + ct*16 + n16] = f2b(acc[rt][ct][reg]);
    __syncthreads();
    #pragma unroll
    for (int i = 0; i < 4; ++i) {
      int u = tid + i*256;
      int row = u >> 5, off = (u & 31) * 8;
      *(s16x8*)&feat1[(size_t)((nBase + row)*32 + bt)*256 + off] = *(const s16x8*)&Lb[row*256 + off];
    }
  }
  if constexpr (NPH >= 2) gbar(bar + (1*8 + g)*128, sub);

  // ---------------- Phase A1P: agg1 + elu + proj [W2;Wres2] ----------------
  if constexpr (NPH >= 3) {
    float (*wsm)[8][4] = (float(*)[8][4])pool;
    float (*Wp)[256]   = (float(*)[256])(pool + 4096);            // 8192 B
    const int hw2 = tid >> 5, l5 = tid & 31;
    const int c0 = l5 * 8, hh = l5 >> 3;
    s16x8 vA[8], vB[8];
    #pragma unroll
    for (int j = 0; j < 8; ++j) {
      vA[j] = *(const s16x8*)&feat1[(size_t)(ssm[hw2    ][j]*32 + bt)*256 + c0];
      vB[j] = *(const s16x8*)&feat1[(size_t)(ssm[hw2 + 8][j]*32 + bt)*256 + c0];
    }
    ((float4*)Wp)[tid]       = ((const float4*)W2)[tid & 255];
    ((float4*)Wp)[256 + tid] = ((const float4*)Wr2)[tid & 255];
    if (tid < 128) {
      const int nl = tid >> 2, h = tid & 3;
      const int rn = (nBase + nl)*32 + bt;
      const float erv = er1[rn*4 + h];
      float e[8]; float mx = -1e30f;
      #pragma unroll
      for (int j = 0; j < 8; ++j) {
        float v = el1[(ssm[nl][j]*32 + bt)*4 + h] + erv;
        v = v >= 0.f ? v : NEGS * v;
        e[j] = v; mx = fmaxf(mx, v);
      }
      float den = 0.f;
      #pragma unroll
      for (int j = 0; j < 8; ++j) { e[j] = __expf(e[j] - mx); den += e[j]; }
      const float inv = 1.f / den;
      #pragma unroll
      for (int j = 0; j < 8; ++j) wsm[nl][j][h] = e[j] * inv;
    }
    __syncthreads();
    #pragma unroll
    for (int p2 = 0; p2 < 2; ++p2) {
      const int nlA = p2*16 + hw2, nlB = nlA + 8;
      const int rnA = (nBase + nlA)*32 + bt, rnB = (nBase + nlB)*32 + bt;
      if (p2 == 1) {
        #pragma unroll
        for (int j = 0; j < 8; ++j) {
          vA[j] = *(const s16x8*)&feat1[(size_t)(ssm[nlA][j]*32 + bt)*256 + c0];
          vB[j] = *(const s16x8*)&feat1[(size_t)(ssm[nlB][j]*32 + bt)*256 + c0];
        }
      }
      asm volatile("" ::: "memory");
      const s16x8 rrA = h1r[p2][0], rrB = h1r[p2][1];
      float aA[8] = {0,0,0,0,0,0,0,0}, aB[8] = {0,0,0,0,0,0,0,0};
      #pragma unroll
      for (int j = 0; j < 8; ++j) {
        const float wA = wsm[nlA][j][hh], wB = wsm[nlB][j][hh];
        #pragma unroll
        for (int i = 0; i < 8; ++i) {
          aA[i] = fmaf(wA, b2f((unsigned short)vA[j][i]), aA[i]);
          aB[i] = fmaf(wB, b2f((unsigned short)vB[j][i]), aB[i]);
        }
      }
      #pragma unroll
      for (int i = 0; i < 8; ++i) {
        float xA = aA[i] + b2f((unsigned short)rrA[i]);
        float xB = aB[i] + b2f((unsigned short)rrB[i]);
        aA[i] = xA > 0.f ? xA : elu_neg(xA);
        aB[i] = xB > 0.f ? xB : elu_neg(xB);
      }
      #pragma unroll
      for (int o = 0; o < 8; ++o) {
        float4 wa = *(const float4*)&Wp[o][c0];
        float4 wb = *(const float4*)&Wp[o][c0 + 4];
        float pA = aA[0]*wa.x + aA[1]*wa.y + aA[2]*wa.z + aA[3]*wa.w
                 + aA[4]*wb.x + aA[5]*wb.y + aA[6]*wb.z + aA[7]*wb.w;
        float pB = aB[0]*wa.x + aB[1]*wa.y + aB[2]*wa.z + aB[3]*wa.w
                 + aB[4]*wb.x + aB[5]*wb.y + aB[6]*wb.z + aB[7]*wb.w;
        #pragma unroll
        for (int off = 1; off < 32; off <<= 1) {
          pA += __shfl_xor(pA, off);
          pB += __shfl_xor(pB, off);
        }
        if (l5 == 0) {
          if (o < 4) { feat2[rnA*4 + o] = pA; feat2[rnB*4 + o] = pB; }
          else       { res2[rnA*4 + (o-4)] = pA; res2[rnB*4 + (o-4)] = pB; }
        }
      }
    }
  }
  if constexpr (NPH >= 3) {
    gbar(bar + (2*8 + g)*128, sub);
    // ------- Phase A2a: layer-2 aggregate + per-(b,t) tc1 partial -> x1 atomics -------
    if (tid < 128) {
      const int nl = tid >> 2, h = tid & 3;
      const int n = nBase + nl;
      const int rn = n*32 + bt;
      const float av = al2[h], rv = ar2[h];
      const float erv = feat2[rn*4 + h] * rv;
      float f[8], e[8]; float m = -1e30f;
      #pragma unroll
      for (int j = 0; j < 8; ++j) {
        f[j] = feat2[(ssm[nl][j]*32 + bt)*4 + h];
        float v = f[j]*av + erv;
        v = v >= 0.f ? v : NEGS * v;
        e[j] = v; m = fmaxf(m, v);
      }
      float den = 0.f, num = 0.f;
      #pragma unroll
      for (int j = 0; j < 8; ++j) { float ex = __expf(e[j]-m); den += ex; num = fmaf(ex, f[j], num); }
      const float os = num/den + res2[rn*4 + h];
      float po[4];
      #pragma unroll
      for (int o = 0; o < 4; ++o) po[o] = tc1w[(o*4 + h)*8 + t] * os;
      #pragma unroll
      for (int off = 1; off < 4; off <<= 1)
        #pragma unroll
        for (int o = 0; o < 4; ++o) po[o] += __shfl_xor(po[o], off);
      float v = (h==0) ? po[0] : (h==1) ? po[1] : (h==2) ? po[2] : po[3];
      atomicAdd(&x1[(b*4 + h)*1024 + n], v);
    }
  }
}

// ============ head: LN1 -> tc2 -> LN2 -> conv (x1 is only 64KB) ============
__global__ __launch_bounds__(256) void k_fin(
    const float* __restrict__ x1g, const float* __restrict__ tc1b,
    const float* __restrict__ ln1g, const float* __restrict__ ln1b,
    const float* __restrict__ tc2w, const float* __restrict__ tc2b,
    const float* __restrict__ ln2g, const float* __restrict__ ln2b,
    const float* __restrict__ fcw, const float* __restrict__ fcb,
    float* __restrict__ out)
{
  __shared__ __align__(16) float x1s[4][1024];
  __shared__ float x2s[1024];
  __shared__ float redA[4], redB[4];
  __shared__ float redC[4][7];
  const int bb = blockIdx.x, tid = threadIdx.x;
  const int wv = tid >> 6, lane = tid & 63;
  float s = 0.f, qq = 0.f;
  #pragma unroll
  for (int i = 0; i < 4; ++i) {
    const int n = tid + i*256;
    #pragma unroll
    for (int o = 0; o < 4; ++o) {
      float a = x1g[(bb*4 + o)*1024 + n] + tc1b[o];
      x1s[o][n] = a; s += a; qq += a*a;
    }
  }
  #pragma unroll
  for (int o = 32; o > 0; o >>= 1) { s += __shfl_down(s, o); qq += __shfl_down(qq, o); }
  if (lane == 0) { redA[wv] = s; redB[wv] = qq; }
  __syncthreads();
  const float S = redA[0]+redA[1]+redA[2]+redA[3];
  const float Q = redB[0]+redB[1]+redB[2]+redB[3];
  const float mu  = S * (1.f/4096.f);
  const float var = Q * (1.f/4096.f) - mu*mu;
  const float inv = rsqrtf(var + EPSF);
  const float tb = tc2b[0];
  const float r0 = tc2w[0], r1 = tc2w[1], r2 = tc2w[2], r3 = tc2w[3];
  float accv[4]; float s2 = 0.f, q2 = 0.f;
  #pragma unroll
  for (int i = 0; i < 4; ++i) {
    const int n = tid + i*256;
    float4 g4 = *(const float4*)&ln1g[n*4];
    float4 b4 = *(const float4*)&ln1b[n*4];
    float a = tb;
    a = fmaf(r0, (x1s[0][n]-mu)*inv*g4.x + b4.x, a);
    a = fmaf(r1, (x1s[1][n]-mu)*inv*g4.y + b4.y, a);
    a = fmaf(r2, (x1s[2][n]-mu)*inv*g4.z + b4.z, a);
    a = fmaf(r3, (x1s[3][n]-mu)*inv*g4.w + b4.w, a);
    accv[i] = a; s2 += a; q2 += a*a;
  }
  __syncthreads();   // before reusing redA/redB
  #pragma unroll
  for (int o = 32; o > 0; o >>= 1) { s2 += __shfl_down(s2, o); q2 += __shfl_down(q2, o); }
  if (lane == 0) { redA[wv] = s2; redB[wv] = q2; }
  __syncthreads();
  const float S2 = redA[0]+redA[1]+redA[2]+redA[3];
  const float Q2 = redB[0]+redB[1]+redB[2]+redB[3];
  const float mu2  = S2 * (1.f/1024.f);
  const float inv2 = rsqrtf(Q2 * (1.f/1024.f) - mu2*mu2 + EPSF);
  #pragma unroll
  for (int i = 0; i < 4; ++i) {
    const int n = tid + i*256;
    x2s[n] = (accv[i] - mu2) * inv2 * ln2g[n] + ln2b[n];
  }
  __syncthreads();
  float pc[7] = {0.f,0.f,0.f,0.f,0.f,0.f,0.f};
  for (int k = tid; k < 1018; k += 256) {
    const float fw = fcw[k];
    #pragma unroll
    for (int c = 0; c < 7; ++c) pc[c] = fmaf(x2s[k + c], fw, pc[c]);
  }
  #pragma unroll
  for (int o = 32; o > 0; o >>= 1)
    #pragma unroll
    for (int c = 0; c < 7; ++c) pc[c] += __shfl_down(pc[c], o);
  if (lane == 0) {
    #pragma unroll
    for (int c = 0; c < 7; ++c) redC[wv][c] = pc[c];
  }
  __syncthreads();
  if (tid < 7)
    out[bb*7 + tid] = redC[0][tid] + redC[1][tid] + redC[2][tid] + redC[3][tid] + fcb[0];
}

extern "C" void kernel_launch(void* const* d_in, const int* in_sizes, int n_in,
                              void* d_out, int out_size, void* d_ws, size_t ws_size,
                              hipStream_t stream)
{
  const float* inp  = (const float*)d_in[0];
  const int*   src  = (const int*)  d_in[1];
  const float* W0   = (const float*)d_in[3];
  const float* al0  = (const float*)d_in[4];
  const float* ar0  = (const float*)d_in[5];
  const float* W1   = (const float*)d_in[6];
  const float* al1  = (const float*)d_in[7];
  const float* ar1  = (const float*)d_in[8];
  const float* W2   = (const float*)d_in[9];
  const float* al2  = (const float*)d_in[10];
  const float* ar2  = (const float*)d_in[11];
  const float* Wr2  = (const float*)d_in[12];
  const float* tc1w = (const float*)d_in[13];
  const float* tc1b = (const float*)d_in[14];
  const float* ln1g = (const float*)d_in[15];
  const float* ln1b = (const float*)d_in[16];
  const float* tc2w = (const float*)d_in[17];
  const float* tc2b = (const float*)d_in[18];
  const float* ln2g = (const float*)d_in[19];
  const float* ln2b = (const float*)d_in[20];
  const float* fcw  = (const float*)d_in[21];
  const float* fcb  = (const float*)d_in[22];
  float* out = (float*)d_out;

  unsigned short* W1bX   = (unsigned short*)d_ws;    // 8 XCD copies: 524,288 shorts
  unsigned short* featb0 = W1bX   + 524288;          // 8,388,608
  unsigned short* featb1 = featb0 + 8388608;         // 8,388,608
  float* el0   = (float*)(featb1 + 8388608);         // 131,072 each
  float* er0   = el0   + 131072;
  float* el1   = er0   + 131072;
  float* er1   = el1   + 131072;
  float* feat2 = er1   + 131072;
  float* res2  = feat2 + 131072;
  float* x1    = res2  + 131072;                     // 16,384 floats (64 KB)
  int*   bar   = (int*)(x1 + 16384);                 // real 3072 + kp1 1024 + kp2 2048 ints

  // zero x1 accumulator (64KB) + all barrier state (24KB) in one memset
  hipMemsetAsync(x1, 0, 16384*4 + 24576, stream);
  // real compute path (identical to round 7)
  k_mega<3><<<dim3(1024), dim3(256), 0, stream>>>(inp, src, W0, al0, ar0, W1, al1, ar1,
                                                  W2, al2, ar2, Wr2, tc1w,
                                                  W1bX, featb0, featb1,
                                                  el0, er0, el1, er1, feat2, res2, x1, bar);
  k_fin<<<dim3(4), dim3(256), 0, stream>>>(x1, tc1b, ln1g, ln1b, tc2w, tc2b,
                                           ln2g, ln2b, fcw, fcb, out);
  // attribution probes (output already produced; re-run truncated variants on
  // the same buffers with fresh one-shot barrier slots):
  //   T(F0) = kp1;  T(A0F1) = kp2 - kp1;  T(A1P+A2a) = k_mega<3> - kp2
  k_mega<1><<<dim3(1024), dim3(256), 0, stream>>>(inp, src, W0, al0, ar0, W1, al1, ar1,
                                                  W2, al2, ar2, Wr2, tc1w,
                                                  W1bX, featb0, featb1,
                                                  el0, er0, el1, er1, feat2, res2, x1,
                                                  bar + 3072);
  k_mega<2><<<dim3(1024), dim3(256), 0, stream>>>(inp, src, W0, al0, ar0, W1, al1, ar1,
                                                  W2, al2, ar2, Wr2, tc1w,
                                                  W1bX, featb0, featb1,
                                                  el0, er0, el1, er1, feat2, res2, x1,
                                                  bar + 4096);
}

// Round 9
// 171.238 us; speedup vs baseline: 1.3753x; 1.3753x over previous
//
#include <hip/hip_runtime.h>
#include <math.h>

#define NEGS 0.2f
#define EPSF 1e-5f

typedef short s16x8 __attribute__((ext_vector_type(8)));
typedef float f32x4 __attribute__((ext_vector_type(4)));

__device__ __forceinline__ float b2f(unsigned short u) {
  union { unsigned int i; float f; } v; v.i = ((unsigned int)u) << 16; return v.f;
}
__device__ __forceinline__ unsigned short f2b(float f) {
  union { float f; unsigned int i; } v; v.f = f;
  unsigned int x = v.i;
  return (unsigned short)((x + 0x7fffu + ((x >> 16) & 1u)) >> 16);
}
// fast ELU negative branch: exp(x)-1 via hw exp; |err| ~1e-7 << bf16 tolerance
__device__ __forceinline__ float elu_neg(float x) { return __expf(x) - 1.f; }

// One-shot group barrier among 128 same-XCD blocks. slot = 128 ints (512B):
// 4 sub-counters at slot[0/16/32/48], master at slot[64], flag at slot[96].
// All arrival RMWs RELAXED (producer data already drained to the XCD-shared
// L2 by __syncthreads' vmcnt(0)); the ONLY release is the closing block's
// flag store. Pollers spin RELAXED (zero cache maintenance). Bounded spin.
__device__ __forceinline__ void gbar(int* slot, int sub) {
  __syncthreads();
  if (threadIdx.x == 0) {
    int old = __hip_atomic_fetch_add(slot + sub*16, 1, __ATOMIC_RELAXED, __HIP_MEMORY_SCOPE_AGENT);
    if (old == 31) {
      int om = __hip_atomic_fetch_add(slot + 64, 1, __ATOMIC_RELAXED, __HIP_MEMORY_SCOPE_AGENT);
      if (om == 3)
        __hip_atomic_store(slot + 96, 1, __ATOMIC_RELEASE, __HIP_MEMORY_SCOPE_AGENT);
    }
    int it = 0;
    while (__hip_atomic_load(slot + 96, __ATOMIC_RELAXED, __HIP_MEMORY_SCOPE_AGENT) == 0) {
      __builtin_amdgcn_s_sleep(2);
      if (++it > (1 << 22)) break;
    }
  }
  __syncthreads();
}

// ============ mega kernel: feat0 -> agg0+feat1 -> agg1+MFMAproj -> agg2+tc1 ============
// grid 1024 x 256, 4 blocks/CU, all resident. Per-XCD groups of 128 blocks
// sync via gbar. h1 residual in registers. A1P projection done with MFMA
// (h2 staged bf16 in LDS, [W2;Wres2] bf16 in LDS); res2 + self-feat2 stay in
// LDS across the barrier (no global round-trip).
__global__ __launch_bounds__(256, 4) void k_mega(
    const float* __restrict__ inp, const int* __restrict__ src,
    const float* __restrict__ W0, const float* __restrict__ al0, const float* __restrict__ ar0,
    const float* __restrict__ W1, const float* __restrict__ al1, const float* __restrict__ ar1,
    const float* __restrict__ W2, const float* __restrict__ al2, const float* __restrict__ ar2,
    const float* __restrict__ Wr2, const float* __restrict__ tc1w,
    unsigned short* __restrict__ W1bX, unsigned short* __restrict__ feat0,
    unsigned short* __restrict__ feat1,
    float* __restrict__ el0, float* __restrict__ er0,
    float* __restrict__ el1, float* __restrict__ er1,
    float* __restrict__ feat2,
    float* __restrict__ x1, int* bar)
{
  __shared__ __align__(16) char pool[27392];
  // persistent regions:
  //   ssm   @26368 (1024B)      — src indices, written in F0, read everywhere
  //   res_s @25344 (512B), f2_s @25856 (512B) — written in A1P, read in A2a
  int   (*ssm)[8]  = (int(*)[8])(pool + 26368);
  float (*res_s)[4] = (float(*)[4])(pool + 25344);
  float (*f2_s)[4]  = (float(*)[4])(pool + 25856);
  const int tid = threadIdx.x;
  const int bid = blockIdx.x;
  const int g     = bid & 7;                  // XCD group
  const int bt    = g*4 + ((bid >> 3) & 3);   // XCD-aligned bt slice
  const int nBase = (bid >> 5) * 32;          // 32-node chunk
  const int sub   = (bid >> 3) & 3;           // barrier sub-counter
  const int b = bt >> 3, t = bt & 7;
  const int w = tid >> 6, lane = tid & 63, n16 = lane & 15, q = lane >> 4;

  s16x8 h1r[2][2];   // register-resident h1 slice: [p2][A/B]

  // ---------------- Phase F0: feat0 = (inp^T) @ W0^T ----------------
  {
    unsigned short (*At)[72] = (unsigned short(*)[72])pool;       // 4608 B
    unsigned short *Lb = (unsigned short*)(pool + 4608);          // 16384 B
    ((int*)ssm)[tid] = src[nBase*8 + tid];    // persistent: used by all phases
    s16x8 bf[2][4];
    #pragma unroll
    for (int kc = 0; kc < 2; ++kc)
      #pragma unroll
      for (int ct = 0; ct < 4; ++ct) {
        const float* p = &W0[(size_t)((w*4 + ct)*16 + n16)*64 + kc*32 + q*8];
        float4 wa = *(const float4*)p;
        float4 wb = *(const float4*)(p + 4);
        s16x8 o;
        o[0]=(short)f2b(wa.x); o[1]=(short)f2b(wa.y); o[2]=(short)f2b(wa.z); o[3]=(short)f2b(wa.w);
        o[4]=(short)f2b(wb.x); o[5]=(short)f2b(wb.y); o[6]=(short)f2b(wb.z); o[7]=(short)f2b(wb.w);
        bf[kc][ct] = o;
      }
    {
      const int nn = tid & 7, cg = tid >> 3;    // 8 node-quads x 32 ch-slots
      #pragma unroll
      for (int c2 = 0; c2 < 2; ++c2) {
        const int ch = cg + c2*32;
        float4 v = *(const float4*)&inp[((size_t)(b*64 + ch)*8 + t)*1024 + nBase + nn*4];
        At[nn*4 + 0][ch] = f2b(v.x);
        At[nn*4 + 1][ch] = f2b(v.y);
        At[nn*4 + 2][ch] = f2b(v.z);
        At[nn*4 + 3][ch] = f2b(v.w);
      }
    }
    __syncthreads();
    f32x4 acc[2][4];
    #pragma unroll
    for (int rt = 0; rt < 2; ++rt)
      #pragma unroll
      for (int ct = 0; ct < 4; ++ct) acc[rt][ct] = (f32x4){0.f,0.f,0.f,0.f};
    #pragma unroll
    for (int kc = 0; kc < 2; ++kc) {
      s16x8 af[2];
      #pragma unroll
      for (int rt = 0; rt < 2; ++rt)
        af[rt] = *(const s16x8*)&At[rt*16 + n16][kc*32 + q*8];
      #pragma unroll
      for (int rt = 0; rt < 2; ++rt)
        #pragma unroll
        for (int ct = 0; ct < 4; ++ct)
          acc[rt][ct] = __builtin_amdgcn_mfma_f32_16x16x32_bf16(af[rt], bf[kc][ct], acc[rt][ct], 0, 0, 0);
    }
    float alv[4], arv[4];
    #pragma unroll
    for (int ct = 0; ct < 4; ++ct) {
      alv[ct] = al0[w*64 + ct*16 + n16];
      arv[ct] = ar0[w*64 + ct*16 + n16];
    }
    #pragma unroll
    for (int rt = 0; rt < 2; ++rt) {
      #pragma unroll
      for (int reg = 0; reg < 4; ++reg) {
        float pl = acc[rt][0][reg]*alv[0] + acc[rt][1][reg]*alv[1]
                 + acc[rt][2][reg]*alv[2] + acc[rt][3][reg]*alv[3];
        float pr = acc[rt][0][reg]*arv[0] + acc[rt][1][reg]*arv[1]
                 + acc[rt][2][reg]*arv[2] + acc[rt][3][reg]*arv[3];
        #pragma unroll
        for (int o = 1; o < 16; o <<= 1) { pl += __shfl_xor(pl, o); pr += __shfl_xor(pr, o); }
        if (n16 == 0) {
          int r = (nBase + rt*16 + q*4 + reg)*32 + bt;
          el0[r*4 + w] = pl;
          er0[r*4 + w] = pr;
        }
      }
    }
    #pragma unroll
    for (int rt = 0; rt < 2; ++rt)
      #pragma unroll
      for (int ct = 0; ct < 4; ++ct)
        #pragma unroll
        for (int reg = 0; reg < 4; ++reg)
          Lb[(rt*16 + q*4 + reg)*256 + w*64 + ct*16 + n16] = f2b(acc[rt][ct][reg]);
    __syncthreads();
    #pragma unroll
    for (int i = 0; i < 4; ++i) {
      int u = tid + i*256;
      int m = u >> 5, off = (u & 31) * 8;
      *(s16x8*)&feat0[(size_t)((nBase + m)*32 + bt)*256 + off] = *(const s16x8*)&Lb[m*256 + off];
    }
    // per-XCD W1 -> bf16 copy (each group converts its own copy; stays in its L2)
    if (tid < 128) {
      const int j = ((bid >> 3) << 9) + tid*4;   // 128 blocks/group * 512 = 65536
      float4 w4 = *(const float4*)&W1[j];
      ushort4 o4; o4.x=f2b(w4.x); o4.y=f2b(w4.y); o4.z=f2b(w4.z); o4.w=f2b(w4.w);
      *(ushort4*)&W1bX[(size_t)g*65536 + j] = o4;
    }
  }
  gbar(bar + (0*8 + g)*128, sub);

  // ---------------- Phase A0F1: agg0 + feat1 ----------------
  {
    float (*wsm)[8][4] = (float(*)[8][4])pool;                    // 4096 B
    unsigned short *smbuf = (unsigned short*)(pool + 4096);       // 16896 B
    unsigned short (*At)[264] = (unsigned short(*)[264])smbuf;
    unsigned short *Lb = smbuf;
    const int hw2 = tid >> 5, l5 = tid & 31;
    const int c0 = l5 * 8, hh = l5 >> 3;
    s16x8 vA[8], vB[8];
    #pragma unroll
    for (int j = 0; j < 8; ++j) {
      vA[j] = *(const s16x8*)&feat0[(size_t)(ssm[hw2    ][j]*32 + bt)*256 + c0];
      vB[j] = *(const s16x8*)&feat0[(size_t)(ssm[hw2 + 8][j]*32 + bt)*256 + c0];
    }
    if (tid < 128) {
      const int nl = tid >> 2, h = tid & 3;
      const int rn = (nBase + nl)*32 + bt;
      const float erv = er0[rn*4 + h];
      float e[8]; float mx = -1e30f;
      #pragma unroll
      for (int j = 0; j < 8; ++j) {
        float v = el0[(ssm[nl][j]*32 + bt)*4 + h] + erv;
        v = v >= 0.f ? v : NEGS * v;
        e[j] = v; mx = fmaxf(mx, v);
      }
      float den = 0.f;
      #pragma unroll
      for (int j = 0; j < 8; ++j) { e[j] = __expf(e[j] - mx); den += e[j]; }
      const float inv = 1.f / den;
      #pragma unroll
      for (int j = 0; j < 8; ++j) wsm[nl][j][h] = e[j] * inv;
    }
    __syncthreads();
    #pragma unroll
    for (int p2 = 0; p2 < 2; ++p2) {
      const int nlA = p2*16 + hw2, nlB = nlA + 8;
      if (p2 == 1) {
        #pragma unroll
        for (int j = 0; j < 8; ++j) {
          vA[j] = *(const s16x8*)&feat0[(size_t)(ssm[nlA][j]*32 + bt)*256 + c0];
          vB[j] = *(const s16x8*)&feat0[(size_t)(ssm[nlB][j]*32 + bt)*256 + c0];
        }
      }
      asm volatile("" ::: "memory");
      float aA[8] = {0,0,0,0,0,0,0,0}, aB[8] = {0,0,0,0,0,0,0,0};
      #pragma unroll
      for (int j = 0; j < 8; ++j) {
        const float wA = wsm[nlA][j][hh], wB = wsm[nlB][j][hh];
        #pragma unroll
        for (int i = 0; i < 8; ++i) {
          aA[i] = fmaf(wA, b2f((unsigned short)vA[j][i]), aA[i]);
          aB[i] = fmaf(wB, b2f((unsigned short)vB[j][i]), aB[i]);
        }
      }
      s16x8 oA, oB;
      #pragma unroll
      for (int i = 0; i < 8; ++i) {
        float xA = aA[i] > 0.f ? aA[i] : elu_neg(aA[i]);
        float xB = aB[i] > 0.f ? aB[i] : elu_neg(aB[i]);
        oA[i] = (short)f2b(xA); oB[i] = (short)f2b(xB);
      }
      *(s16x8*)&At[nlA][c0] = oA;
      *(s16x8*)&At[nlB][c0] = oB;
      h1r[p2][0] = oA;            // registers, consumed in A1P by this thread
      h1r[p2][1] = oB;
    }
    __syncthreads();
    f32x4 acc[2][4];
    #pragma unroll
    for (int rt = 0; rt < 2; ++rt)
      #pragma unroll
      for (int ct = 0; ct < 4; ++ct) acc[rt][ct] = (f32x4){0.f,0.f,0.f,0.f};
    const unsigned short* W1g = W1bX + (size_t)g*65536;
    #pragma unroll
    for (int kc = 0; kc < 8; ++kc) {
      s16x8 af[2], bfr[4];
      #pragma unroll
      for (int rt = 0; rt < 2; ++rt)
        af[rt] = *(const s16x8*)&At[rt*16 + n16][kc*32 + q*8];
      #pragma unroll
      for (int ct = 0; ct < 4; ++ct)
        bfr[ct] = *(const s16x8*)&W1g[(size_t)((w*4 + ct)*16 + n16)*256 + kc*32 + q*8];
      #pragma unroll
      for (int rt = 0; rt < 2; ++rt)
        #pragma unroll
        for (int ct = 0; ct < 4; ++ct)
          acc[rt][ct] = __builtin_amdgcn_mfma_f32_16x16x32_bf16(af[rt], bfr[ct], acc[rt][ct], 0, 0, 0);
    }
    float alv[4], arv[4];
    #pragma unroll
    for (int ct = 0; ct < 4; ++ct) {
      alv[ct] = al1[w*64 + ct*16 + n16];
      arv[ct] = ar1[w*64 + ct*16 + n16];
    }
    #pragma unroll
    for (int rt = 0; rt < 2; ++rt) {
      #pragma unroll
      for (int reg = 0; reg < 4; ++reg) {
        float pl = acc[rt][0][reg]*alv[0] + acc[rt][1][reg]*alv[1]
                 + acc[rt][2][reg]*alv[2] + acc[rt][3][reg]*alv[3];
        float pr = acc[rt][0][reg]*arv[0] + acc[rt][1][reg]*arv[1]
                 + acc[rt][2][reg]*arv[2] + acc[rt][3][reg]*arv[3];
        #pragma unroll
        for (int o = 1; o < 16; o <<= 1) { pl += __shfl_xor(pl, o); pr += __shfl_xor(pr, o); }
        if (n16 == 0) {
          int r = (nBase + rt*16 + q*4 + reg)*32 + bt;
          el1[r*4 + w] = pl;
          er1[r*4 + w] = pr;
        }
      }
    }
    __syncthreads();   // At aliases Lb: all At reads must finish first
    #pragma unroll
    for (int rt = 0; rt < 2; ++rt)
      #pragma unroll
      for (int ct = 0; ct < 4; ++ct)
        #pragma unroll
        for (int reg = 0; reg < 4; ++reg)
          Lb[(rt*16 + q*4 + reg)*256 + w*64 + ct*16 + n16] = f2b(acc[rt][ct][reg]);
    __syncthreads();
    #pragma unroll
    for (int i = 0; i < 4; ++i) {
      int u = tid + i*256;
      int row = u >> 5, off = (u & 31) * 8;
      *(s16x8*)&feat1[(size_t)((nBase + row)*32 + bt)*256 + off] = *(const s16x8*)&Lb[row*256 + off];
    }
  }
  gbar(bar + (1*8 + g)*128, sub);

  // ------ Phase A1P: agg1 + elu -> LDS bf16; proj [W2;Wres2] via MFMA ------
  {
    float (*wsm)[8][4] = (float(*)[8][4])pool;                        // 4096 B
    unsigned short (*At2)[264] = (unsigned short(*)[264])(pool + 4096);  // 16896 B
    unsigned short (*Wcb)[272] = (unsigned short(*)[272])(pool + 20992); // 4352 B
    const int hw2 = tid >> 5, l5 = tid & 31;
    const int c0 = l5 * 8, hh = l5 >> 3;
    s16x8 vA[8], vB[8];
    #pragma unroll
    for (int j = 0; j < 8; ++j) {
      vA[j] = *(const s16x8*)&feat1[(size_t)(ssm[hw2    ][j]*32 + bt)*256 + c0];
      vB[j] = *(const s16x8*)&feat1[(size_t)(ssm[hw2 + 8][j]*32 + bt)*256 + c0];
    }
    // stage [W2;Wres2] -> bf16 LDS rows 0..7 (8 x 256, padded stride 272)
    {
      const int r = tid >> 5, c8 = (tid & 31) * 8;
      const float* sw = (r < 4) ? &W2[r*256 + c8] : &Wr2[(r-4)*256 + c8];
      float4 aa = *(const float4*)sw;
      float4 bb = *(const float4*)(sw + 4);
      s16x8 o;
      o[0]=(short)f2b(aa.x); o[1]=(short)f2b(aa.y); o[2]=(short)f2b(aa.z); o[3]=(short)f2b(aa.w);
      o[4]=(short)f2b(bb.x); o[5]=(short)f2b(bb.y); o[6]=(short)f2b(bb.z); o[7]=(short)f2b(bb.w);
      *(s16x8*)&Wcb[r][c8] = o;
    }
    if (tid < 128) {
      const int nl = tid >> 2, h = tid & 3;
      const int rn = (nBase + nl)*32 + bt;
      const float erv = er1[rn*4 + h];
      float e[8]; float mx = -1e30f;
      #pragma unroll
      for (int j = 0; j < 8; ++j) {
        float v = el1[(ssm[nl][j]*32 + bt)*4 + h] + erv;
        v = v >= 0.f ? v : NEGS * v;
        e[j] = v; mx = fmaxf(mx, v);
      }
      float den = 0.f;
      #pragma unroll
      for (int j = 0; j < 8; ++j) { e[j] = __expf(e[j] - mx); den += e[j]; }
      const float inv = 1.f / den;
      #pragma unroll
      for (int j = 0; j < 8; ++j) wsm[nl][j][h] = e[j] * inv;
    }
    __syncthreads();
    #pragma unroll
    for (int p2 = 0; p2 < 2; ++p2) {
      const int nlA = p2*16 + hw2, nlB = nlA + 8;
      if (p2 == 1) {
        #pragma unroll
        for (int j = 0; j < 8; ++j) {
          vA[j] = *(const s16x8*)&feat1[(size_t)(ssm[nlA][j]*32 + bt)*256 + c0];
          vB[j] = *(const s16x8*)&feat1[(size_t)(ssm[nlB][j]*32 + bt)*256 + c0];
        }
      }
      asm volatile("" ::: "memory");
      const s16x8 rrA = h1r[p2][0], rrB = h1r[p2][1];
      float aA[8] = {0,0,0,0,0,0,0,0}, aB[8] = {0,0,0,0,0,0,0,0};
      #pragma unroll
      for (int j = 0; j < 8; ++j) {
        const float wA = wsm[nlA][j][hh], wB = wsm[nlB][j][hh];
        #pragma unroll
        for (int i = 0; i < 8; ++i) {
          aA[i] = fmaf(wA, b2f((unsigned short)vA[j][i]), aA[i]);
          aB[i] = fmaf(wB, b2f((unsigned short)vB[j][i]), aB[i]);
        }
      }
      s16x8 oA, oB;
      #pragma unroll
      for (int i = 0; i < 8; ++i) {
        float xA = aA[i] + b2f((unsigned short)rrA[i]);
        float xB = aB[i] + b2f((unsigned short)rrB[i]);
        xA = xA > 0.f ? xA : elu_neg(xA);
        xB = xB > 0.f ? xB : elu_neg(xB);
        oA[i] = (short)f2b(xA); oB[i] = (short)f2b(xB);
      }
      *(s16x8*)&At2[nlA][c0] = oA;
      *(s16x8*)&At2[nlB][c0] = oB;
    }
    __syncthreads();
    // MFMA proj: h2[32x256] @ Wcat^T[8x256]. Waves 0/1 own row-tile rt = w.
    if (w < 2) {
      const int rt = w;
      f32x4 acc = (f32x4){0.f,0.f,0.f,0.f};
      #pragma unroll
      for (int kc = 0; kc < 8; ++kc) {
        s16x8 af = *(const s16x8*)&At2[rt*16 + n16][kc*32 + q*8];
        s16x8 bfr = (s16x8){0,0,0,0,0,0,0,0};
        if (n16 < 8) bfr = *(const s16x8*)&Wcb[n16][kc*32 + q*8];
        acc = __builtin_amdgcn_mfma_f32_16x16x32_bf16(af, bfr, acc, 0, 0, 0);
      }
      // C layout: col (output o) = n16, row (node) = rt*16 + q*4 + reg
      #pragma unroll
      for (int reg = 0; reg < 4; ++reg) {
        const int nl = rt*16 + q*4 + reg;
        const float v = acc[reg];
        if (n16 < 4) {
          feat2[((size_t)(nBase + nl)*32 + bt)*4 + n16] = v;   // global: gathered by peers
          f2_s[nl][n16] = v;                                   // LDS: self-use in A2a
        } else if (n16 < 8) {
          res_s[nl][n16 - 4] = v;                              // LDS only
        }
      }
    }
  }
  gbar(bar + (2*8 + g)*128, sub);

  // ------- Phase A2a: layer-2 aggregate + per-(b,t) tc1 partial -> x1 atomics -------
  if (tid < 128) {
    const int nl = tid >> 2, h = tid & 3;
    const int n = nBase + nl;
    const float av = al2[h], rv = ar2[h];
    const float erv = f2_s[nl][h] * rv;     // self feat2 from LDS
    float f[8], e[8]; float m = -1e30f;
    #pragma unroll
    for (int j = 0; j < 8; ++j) {
      f[j] = feat2[(ssm[nl][j]*32 + bt)*4 + h];
      float v = f[j]*av + erv;
      v = v >= 0.f ? v : NEGS * v;
      e[j] = v; m = fmaxf(m, v);
    }
    float den = 0.f, num = 0.f;
    #pragma unroll
    for (int j = 0; j < 8; ++j) { float ex = __expf(e[j]-m); den += ex; num = fmaf(ex, f[j], num); }
    const float os = num/den + res_s[nl][h];  // residual from LDS
    // partial einsum: x1[b][o][n] += tc1w[o][h][t] * os, summed over this 4-lane h-group
    float po[4];
    #pragma unroll
    for (int o = 0; o < 4; ++o) po[o] = tc1w[(o*4 + h)*8 + t] * os;
    #pragma unroll
    for (int off = 1; off < 4; off <<= 1)
      #pragma unroll
      for (int o = 0; o < 4; ++o) po[o] += __shfl_xor(po[o], off);
    float v = (h==0) ? po[0] : (h==1) ? po[1] : (h==2) ? po[2] : po[3];
    atomicAdd(&x1[(b*4 + h)*1024 + n], v);
  }
}

// ============ head: LN1 -> tc2 -> LN2 -> conv (x1 is only 64KB) ============
__global__ __launch_bounds__(256) void k_fin(
    const float* __restrict__ x1g, const float* __restrict__ tc1b,
    const float* __restrict__ ln1g, const float* __restrict__ ln1b,
    const float* __restrict__ tc2w, const float* __restrict__ tc2b,
    const float* __restrict__ ln2g, const float* __restrict__ ln2b,
    const float* __restrict__ fcw, const float* __restrict__ fcb,
    float* __restrict__ out)
{
  __shared__ __align__(16) float x1s[4][1024];
  __shared__ float x2s[1024];
  __shared__ float redA[4], redB[4];
  __shared__ float redC[4][7];
  const int bb = blockIdx.x, tid = threadIdx.x;
  const int wv = tid >> 6, lane = tid & 63;
  float s = 0.f, qq = 0.f;
  #pragma unroll
  for (int i = 0; i < 4; ++i) {
    const int n = tid + i*256;
    #pragma unroll
    for (int o = 0; o < 4; ++o) {
      float a = x1g[(bb*4 + o)*1024 + n] + tc1b[o];
      x1s[o][n] = a; s += a; qq += a*a;
    }
  }
  #pragma unroll
  for (int o = 32; o > 0; o >>= 1) { s += __shfl_down(s, o); qq += __shfl_down(qq, o); }
  if (lane == 0) { redA[wv] = s; redB[wv] = qq; }
  __syncthreads();
  const float S = redA[0]+redA[1]+redA[2]+redA[3];
  const float Q = redB[0]+redB[1]+redB[2]+redB[3];
  const float mu  = S * (1.f/4096.f);
  const float var = Q * (1.f/4096.f) - mu*mu;
  const float inv = rsqrtf(var + EPSF);
  const float tb = tc2b[0];
  const float r0 = tc2w[0], r1 = tc2w[1], r2 = tc2w[2], r3 = tc2w[3];
  float accv[4]; float s2 = 0.f, q2 = 0.f;
  #pragma unroll
  for (int i = 0; i < 4; ++i) {
    const int n = tid + i*256;
    float4 g4 = *(const float4*)&ln1g[n*4];
    float4 b4 = *(const float4*)&ln1b[n*4];
    float a = tb;
    a = fmaf(r0, (x1s[0][n]-mu)*inv*g4.x + b4.x, a);
    a = fmaf(r1, (x1s[1][n]-mu)*inv*g4.y + b4.y, a);
    a = fmaf(r2, (x1s[2][n]-mu)*inv*g4.z + b4.z, a);
    a = fmaf(r3, (x1s[3][n]-mu)*inv*g4.w + b4.w, a);
    accv[i] = a; s2 += a; q2 += a*a;
  }
  __syncthreads();   // before reusing redA/redB
  #pragma unroll
  for (int o = 32; o > 0; o >>= 1) { s2 += __shfl_down(s2, o); q2 += __shfl_down(q2, o); }
  if (lane == 0) { redA[wv] = s2; redB[wv] = q2; }
  __syncthreads();
  const float S2 = redA[0]+redA[1]+redA[2]+redA[3];
  const float Q2 = redB[0]+redB[1]+redB[2]+redB[3];
  const float mu2  = S2 * (1.f/1024.f);
  const float inv2 = rsqrtf(Q2 * (1.f/1024.f) - mu2*mu2 + EPSF);
  #pragma unroll
  for (int i = 0; i < 4; ++i) {
    const int n = tid + i*256;
    x2s[n] = (accv[i] - mu2) * inv2 * ln2g[n] + ln2b[n];
  }
  __syncthreads();
  float pc[7] = {0.f,0.f,0.f,0.f,0.f,0.f,0.f};
  for (int k = tid; k < 1018; k += 256) {
    const float fw = fcw[k];
    #pragma unroll
    for (int c = 0; c < 7; ++c) pc[c] = fmaf(x2s[k + c], fw, pc[c]);
  }
  #pragma unroll
  for (int o = 32; o > 0; o >>= 1)
    #pragma unroll
    for (int c = 0; c < 7; ++c) pc[c] += __shfl_down(pc[c], o);
  if (lane == 0) {
    #pragma unroll
    for (int c = 0; c < 7; ++c) redC[wv][c] = pc[c];
  }
  __syncthreads();
  if (tid < 7)
    out[bb*7 + tid] = redC[0][tid] + redC[1][tid] + redC[2][tid] + redC[3][tid] + fcb[0];
}

extern "C" void kernel_launch(void* const* d_in, const int* in_sizes, int n_in,
                              void* d_out, int out_size, void* d_ws, size_t ws_size,
                              hipStream_t stream)
{
  const float* inp  = (const float*)d_in[0];
  const int*   src  = (const int*)  d_in[1];
  const float* W0   = (const float*)d_in[3];
  const float* al0  = (const float*)d_in[4];
  const float* ar0  = (const float*)d_in[5];
  const float* W1   = (const float*)d_in[6];
  const float* al1  = (const float*)d_in[7];
  const float* ar1  = (const float*)d_in[8];
  const float* W2   = (const float*)d_in[9];
  const float* al2  = (const float*)d_in[10];
  const float* ar2  = (const float*)d_in[11];
  const float* Wr2  = (const float*)d_in[12];
  const float* tc1w = (const float*)d_in[13];
  const float* tc1b = (const float*)d_in[14];
  const float* ln1g = (const float*)d_in[15];
  const float* ln1b = (const float*)d_in[16];
  const float* tc2w = (const float*)d_in[17];
  const float* tc2b = (const float*)d_in[18];
  const float* ln2g = (const float*)d_in[19];
  const float* ln2b = (const float*)d_in[20];
  const float* fcw  = (const float*)d_in[21];
  const float* fcb  = (const float*)d_in[22];
  float* out = (float*)d_out;

  unsigned short* W1bX   = (unsigned short*)d_ws;    // 8 XCD copies: 524,288 shorts
  unsigned short* featb0 = W1bX   + 524288;          // 8,388,608
  unsigned short* featb1 = featb0 + 8388608;         // 8,388,608
  float* el0   = (float*)(featb1 + 8388608);         // 131,072 each
  float* er0   = el0   + 131072;
  float* el1   = er0   + 131072;
  float* er1   = el1   + 131072;
  float* feat2 = er1   + 131072;
  float* x1    = feat2 + 131072;                     // 16,384 floats (64 KB)
  int*   bar   = (int*)(x1 + 16384);                 // 3 phases x 8 groups x 512B

  // zero x1 accumulator (64KB) + barrier state (12KB) in one memset
  hipMemsetAsync(x1, 0, 16384*4 + 12288, stream);
  k_mega<<<dim3(1024), dim3(256), 0, stream>>>(inp, src, W0, al0, ar0, W1, al1, ar1,
                                               W2, al2, ar2, Wr2, tc1w,
                                               W1bX, featb0, featb1,
                                               el0, er0, el1, er1, feat2, x1, bar);
  k_fin<<<dim3(4), dim3(256), 0, stream>>>(x1, tc1b, ln1g, ln1b, tc2w, tc2b,
                                           ln2g, ln2b, fcw, fcb, out);
}

// Round 10
// 171.129 us; speedup vs baseline: 1.3761x; 1.0006x over previous
//
#include <hip/hip_runtime.h>
#include <math.h>

#define NEGS 0.2f
#define EPSF 1e-5f

typedef short s16x8 __attribute__((ext_vector_type(8)));
typedef float f32x4 __attribute__((ext_vector_type(4)));

__device__ __forceinline__ float b2f(unsigned short u) {
  union { unsigned int i; float f; } v; v.i = ((unsigned int)u) << 16; return v.f;
}
__device__ __forceinline__ unsigned short f2b(float f) {
  union { float f; unsigned int i; } v; v.f = f;
  unsigned int x = v.i;
  return (unsigned short)((x + 0x7fffu + ((x >> 16) & 1u)) >> 16);
}
// fast ELU negative branch: exp(x)-1 via hw exp; |err| ~1e-7 << bf16 tolerance
__device__ __forceinline__ float elu_neg(float x) { return __expf(x) - 1.f; }

// One-shot group barrier among 128 same-XCD blocks. slot = 128 ints (512B):
// 4 sub-counters at slot[0/16/32/48], master at slot[64], flag at slot[96].
// All arrival RMWs RELAXED (producer data already drained to the XCD-shared
// L2 by __syncthreads' vmcnt(0)); the ONLY release is the closing block's
// flag store. Pollers spin RELAXED (zero cache maintenance). Bounded spin.
__device__ __forceinline__ void gbar(int* slot, int sub) {
  __syncthreads();
  if (threadIdx.x == 0) {
    int old = __hip_atomic_fetch_add(slot + sub*16, 1, __ATOMIC_RELAXED, __HIP_MEMORY_SCOPE_AGENT);
    if (old == 31) {
      int om = __hip_atomic_fetch_add(slot + 64, 1, __ATOMIC_RELAXED, __HIP_MEMORY_SCOPE_AGENT);
      if (om == 3)
        __hip_atomic_store(slot + 96, 1, __ATOMIC_RELEASE, __HIP_MEMORY_SCOPE_AGENT);
    }
    int it = 0;
    while (__hip_atomic_load(slot + 96, __ATOMIC_RELAXED, __HIP_MEMORY_SCOPE_AGENT) == 0) {
      __builtin_amdgcn_s_sleep(2);
      if (++it > (1 << 22)) break;
    }
  }
  __syncthreads();
}

// ============ mega kernel: feat0 -> agg0+feat1 -> agg1+MFMAproj -> agg2+tc1 ============
// grid 1024 x 256, 4 blocks/CU, all resident. Per-XCD groups of 128 blocks
// sync via gbar. h1 residual in registers. A1P projection via MFMA.
// waves_per_eu(4,4): grid is exactly 4 blocks/CU, so occupancy >4 waves/EU is
// unusable — telling the allocator unlocks the 128-VGPR budget so the 16
// gather loads stay hoisted (in flight) across the softmax instead of being
// sunk to their use points (the round-7 failure mode at VGPR=64).
__global__ __attribute__((amdgpu_flat_work_group_size(256, 256)))
           __attribute__((amdgpu_waves_per_eu(4, 4)))
void k_mega(
    const float* __restrict__ inp, const int* __restrict__ src,
    const float* __restrict__ W0, const float* __restrict__ al0, const float* __restrict__ ar0,
    const float* __restrict__ W1, const float* __restrict__ al1, const float* __restrict__ ar1,
    const float* __restrict__ W2, const float* __restrict__ al2, const float* __restrict__ ar2,
    const float* __restrict__ Wr2, const float* __restrict__ tc1w,
    unsigned short* __restrict__ W1bX, unsigned short* __restrict__ feat0,
    unsigned short* __restrict__ feat1,
    float* __restrict__ el0, float* __restrict__ er0,
    float* __restrict__ el1, float* __restrict__ er1,
    float* __restrict__ feat2,
    float* __restrict__ x1, int* bar)
{
  __shared__ __align__(16) char pool[27392];
  // persistent regions:
  //   ssm   @26368 (1024B)      — src indices, written in F0, read everywhere
  //   res_s @25344 (512B), f2_s @25856 (512B) — written in A1P, read in A2a
  int   (*ssm)[8]  = (int(*)[8])(pool + 26368);
  float (*res_s)[4] = (float(*)[4])(pool + 25344);
  float (*f2_s)[4]  = (float(*)[4])(pool + 25856);
  const int tid = threadIdx.x;
  const int bid = blockIdx.x;
  const int g     = bid & 7;                  // XCD group
  const int bt    = g*4 + ((bid >> 3) & 3);   // XCD-aligned bt slice
  const int nBase = (bid >> 5) * 32;          // 32-node chunk
  const int sub   = (bid >> 3) & 3;           // barrier sub-counter
  const int b = bt >> 3, t = bt & 7;
  const int w = tid >> 6, lane = tid & 63, n16 = lane & 15, q = lane >> 4;

  s16x8 h1r[2][2];   // register-resident h1 slice: [p2][A/B]

  // ---------------- Phase F0: feat0 = (inp^T) @ W0^T ----------------
  {
    unsigned short (*At)[72] = (unsigned short(*)[72])pool;       // 4608 B
    unsigned short *Lb = (unsigned short*)(pool + 4608);          // 16384 B
    ((int*)ssm)[tid] = src[nBase*8 + tid];    // persistent: used by all phases
    s16x8 bf[2][4];
    #pragma unroll
    for (int kc = 0; kc < 2; ++kc)
      #pragma unroll
      for (int ct = 0; ct < 4; ++ct) {
        const float* p = &W0[(size_t)((w*4 + ct)*16 + n16)*64 + kc*32 + q*8];
        float4 wa = *(const float4*)p;
        float4 wb = *(const float4*)(p + 4);
        s16x8 o;
        o[0]=(short)f2b(wa.x); o[1]=(short)f2b(wa.y); o[2]=(short)f2b(wa.z); o[3]=(short)f2b(wa.w);
        o[4]=(short)f2b(wb.x); o[5]=(short)f2b(wb.y); o[6]=(short)f2b(wb.z); o[7]=(short)f2b(wb.w);
        bf[kc][ct] = o;
      }
    {
      const int nn = tid & 7, cg = tid >> 3;    // 8 node-quads x 32 ch-slots
      #pragma unroll
      for (int c2 = 0; c2 < 2; ++c2) {
        const int ch = cg + c2*32;
        float4 v = *(const float4*)&inp[((size_t)(b*64 + ch)*8 + t)*1024 + nBase + nn*4];
        At[nn*4 + 0][ch] = f2b(v.x);
        At[nn*4 + 1][ch] = f2b(v.y);
        At[nn*4 + 2][ch] = f2b(v.z);
        At[nn*4 + 3][ch] = f2b(v.w);
      }
    }
    __syncthreads();
    f32x4 acc[2][4];
    #pragma unroll
    for (int rt = 0; rt < 2; ++rt)
      #pragma unroll
      for (int ct = 0; ct < 4; ++ct) acc[rt][ct] = (f32x4){0.f,0.f,0.f,0.f};
    #pragma unroll
    for (int kc = 0; kc < 2; ++kc) {
      s16x8 af[2];
      #pragma unroll
      for (int rt = 0; rt < 2; ++rt)
        af[rt] = *(const s16x8*)&At[rt*16 + n16][kc*32 + q*8];
      #pragma unroll
      for (int rt = 0; rt < 2; ++rt)
        #pragma unroll
        for (int ct = 0; ct < 4; ++ct)
          acc[rt][ct] = __builtin_amdgcn_mfma_f32_16x16x32_bf16(af[rt], bf[kc][ct], acc[rt][ct], 0, 0, 0);
    }
    float alv[4], arv[4];
    #pragma unroll
    for (int ct = 0; ct < 4; ++ct) {
      alv[ct] = al0[w*64 + ct*16 + n16];
      arv[ct] = ar0[w*64 + ct*16 + n16];
    }
    #pragma unroll
    for (int rt = 0; rt < 2; ++rt) {
      #pragma unroll
      for (int reg = 0; reg < 4; ++reg) {
        float pl = acc[rt][0][reg]*alv[0] + acc[rt][1][reg]*alv[1]
                 + acc[rt][2][reg]*alv[2] + acc[rt][3][reg]*alv[3];
        float pr = acc[rt][0][reg]*arv[0] + acc[rt][1][reg]*arv[1]
                 + acc[rt][2][reg]*arv[2] + acc[rt][3][reg]*arv[3];
        #pragma unroll
        for (int o = 1; o < 16; o <<= 1) { pl += __shfl_xor(pl, o); pr += __shfl_xor(pr, o); }
        if (n16 == 0) {
          int r = (nBase + rt*16 + q*4 + reg)*32 + bt;
          el0[r*4 + w] = pl;
          er0[r*4 + w] = pr;
        }
      }
    }
    #pragma unroll
    for (int rt = 0; rt < 2; ++rt)
      #pragma unroll
      for (int ct = 0; ct < 4; ++ct)
        #pragma unroll
        for (int reg = 0; reg < 4; ++reg)
          Lb[(rt*16 + q*4 + reg)*256 + w*64 + ct*16 + n16] = f2b(acc[rt][ct][reg]);
    __syncthreads();
    #pragma unroll
    for (int i = 0; i < 4; ++i) {
      int u = tid + i*256;
      int m = u >> 5, off = (u & 31) * 8;
      *(s16x8*)&feat0[(size_t)((nBase + m)*32 + bt)*256 + off] = *(const s16x8*)&Lb[m*256 + off];
    }
    // per-XCD W1 -> bf16 copy (each group converts its own copy; stays in its L2)
    if (tid < 128) {
      const int j = ((bid >> 3) << 9) + tid*4;   // 128 blocks/group * 512 = 65536
      float4 w4 = *(const float4*)&W1[j];
      ushort4 o4; o4.x=f2b(w4.x); o4.y=f2b(w4.y); o4.z=f2b(w4.z); o4.w=f2b(w4.w);
      *(ushort4*)&W1bX[(size_t)g*65536 + j] = o4;
    }
  }
  gbar(bar + (0*8 + g)*128, sub);

  // ---------------- Phase A0F1: agg0 + feat1 ----------------
  {
    float (*wsm)[8][4] = (float(*)[8][4])pool;                    // 4096 B
    unsigned short *smbuf = (unsigned short*)(pool + 4096);       // 16896 B
    unsigned short (*At)[264] = (unsigned short(*)[264])smbuf;
    unsigned short *Lb = smbuf;
    const int hw2 = tid >> 5, l5 = tid & 31;
    const int c0 = l5 * 8, hh = l5 >> 3;
    s16x8 vA[8], vB[8];
    #pragma unroll
    for (int j = 0; j < 8; ++j) {
      vA[j] = *(const s16x8*)&feat0[(size_t)(ssm[hw2    ][j]*32 + bt)*256 + c0];
      vB[j] = *(const s16x8*)&feat0[(size_t)(ssm[hw2 + 8][j]*32 + bt)*256 + c0];
    }
    if (tid < 128) {
      const int nl = tid >> 2, h = tid & 3;
      const int rn = (nBase + nl)*32 + bt;
      const float erv = er0[rn*4 + h];
      float e[8]; float mx = -1e30f;
      #pragma unroll
      for (int j = 0; j < 8; ++j) {
        float v = el0[(ssm[nl][j]*32 + bt)*4 + h] + erv;
        v = v >= 0.f ? v : NEGS * v;
        e[j] = v; mx = fmaxf(mx, v);
      }
      float den = 0.f;
      #pragma unroll
      for (int j = 0; j < 8; ++j) { e[j] = __expf(e[j] - mx); den += e[j]; }
      const float inv = 1.f / den;
      #pragma unroll
      for (int j = 0; j < 8; ++j) wsm[nl][j][h] = e[j] * inv;
    }
    __syncthreads();
    #pragma unroll
    for (int p2 = 0; p2 < 2; ++p2) {
      const int nlA = p2*16 + hw2, nlB = nlA + 8;
      if (p2 == 1) {
        #pragma unroll
        for (int j = 0; j < 8; ++j) {
          vA[j] = *(const s16x8*)&feat0[(size_t)(ssm[nlA][j]*32 + bt)*256 + c0];
          vB[j] = *(const s16x8*)&feat0[(size_t)(ssm[nlB][j]*32 + bt)*256 + c0];
        }
      }
      asm volatile("" ::: "memory");
      float aA[8] = {0,0,0,0,0,0,0,0}, aB[8] = {0,0,0,0,0,0,0,0};
      #pragma unroll
      for (int j = 0; j < 8; ++j) {
        const float wA = wsm[nlA][j][hh], wB = wsm[nlB][j][hh];
        #pragma unroll
        for (int i = 0; i < 8; ++i) {
          aA[i] = fmaf(wA, b2f((unsigned short)vA[j][i]), aA[i]);
          aB[i] = fmaf(wB, b2f((unsigned short)vB[j][i]), aB[i]);
        }
      }
      s16x8 oA, oB;
      #pragma unroll
      for (int i = 0; i < 8; ++i) {
        float xA = aA[i] > 0.f ? aA[i] : elu_neg(aA[i]);
        float xB = aB[i] > 0.f ? aB[i] : elu_neg(aB[i]);
        oA[i] = (short)f2b(xA); oB[i] = (short)f2b(xB);
      }
      *(s16x8*)&At[nlA][c0] = oA;
      *(s16x8*)&At[nlB][c0] = oB;
      h1r[p2][0] = oA;            // registers, consumed in A1P by this thread
      h1r[p2][1] = oB;
    }
    __syncthreads();
    f32x4 acc[2][4];
    #pragma unroll
    for (int rt = 0; rt < 2; ++rt)
      #pragma unroll
      for (int ct = 0; ct < 4; ++ct) acc[rt][ct] = (f32x4){0.f,0.f,0.f,0.f};
    const unsigned short* W1g = W1bX + (size_t)g*65536;
    #pragma unroll
    for (int kc = 0; kc < 8; ++kc) {
      s16x8 af[2], bfr[4];
      #pragma unroll
      for (int rt = 0; rt < 2; ++rt)
        af[rt] = *(const s16x8*)&At[rt*16 + n16][kc*32 + q*8];
      #pragma unroll
      for (int ct = 0; ct < 4; ++ct)
        bfr[ct] = *(const s16x8*)&W1g[(size_t)((w*4 + ct)*16 + n16)*256 + kc*32 + q*8];
      #pragma unroll
      for (int rt = 0; rt < 2; ++rt)
        #pragma unroll
        for (int ct = 0; ct < 4; ++ct)
          acc[rt][ct] = __builtin_amdgcn_mfma_f32_16x16x32_bf16(af[rt], bfr[ct], acc[rt][ct], 0, 0, 0);
    }
    float alv[4], arv[4];
    #pragma unroll
    for (int ct = 0; ct < 4; ++ct) {
      alv[ct] = al1[w*64 + ct*16 + n16];
      arv[ct] = ar1[w*64 + ct*16 + n16];
    }
    #pragma unroll
    for (int rt = 0; rt < 2; ++rt) {
      #pragma unroll
      for (int reg = 0; reg < 4; ++reg) {
        float pl = acc[rt][0][reg]*alv[0] + acc[rt][1][reg]*alv[1]
                 + acc[rt][2][reg]*alv[2] + acc[rt][3][reg]*alv[3];
        float pr = acc[rt][0][reg]*arv[0] + acc[rt][1][reg]*arv[1]
                 + acc[rt][2][reg]*arv[2] + acc[rt][3][reg]*arv[3];
        #pragma unroll
        for (int o = 1; o < 16; o <<= 1) { pl += __shfl_xor(pl, o); pr += __shfl_xor(pr, o); }
        if (n16 == 0) {
          int r = (nBase + rt*16 + q*4 + reg)*32 + bt;
          el1[r*4 + w] = pl;
          er1[r*4 + w] = pr;
        }
      }
    }
    __syncthreads();   // At aliases Lb: all At reads must finish first
    #pragma unroll
    for (int rt = 0; rt < 2; ++rt)
      #pragma unroll
      for (int ct = 0; ct < 4; ++ct)
        #pragma unroll
        for (int reg = 0; reg < 4; ++reg)
          Lb[(rt*16 + q*4 + reg)*256 + w*64 + ct*16 + n16] = f2b(acc[rt][ct][reg]);
    __syncthreads();
    #pragma unroll
    for (int i = 0; i < 4; ++i) {
      int u = tid + i*256;
      int row = u >> 5, off = (u & 31) * 8;
      *(s16x8*)&feat1[(size_t)((nBase + row)*32 + bt)*256 + off] = *(const s16x8*)&Lb[row*256 + off];
    }
  }
  gbar(bar + (1*8 + g)*128, sub);

  // ------ Phase A1P: agg1 + elu -> LDS bf16; proj [W2;Wres2] via MFMA ------
  {
    float (*wsm)[8][4] = (float(*)[8][4])pool;                        // 4096 B
    unsigned short (*At2)[264] = (unsigned short(*)[264])(pool + 4096);  // 16896 B
    unsigned short (*Wcb)[272] = (unsigned short(*)[272])(pool + 20992); // 4352 B
    const int hw2 = tid >> 5, l5 = tid & 31;
    const int c0 = l5 * 8, hh = l5 >> 3;
    s16x8 vA[8], vB[8];
    #pragma unroll
    for (int j = 0; j < 8; ++j) {
      vA[j] = *(const s16x8*)&feat1[(size_t)(ssm[hw2    ][j]*32 + bt)*256 + c0];
      vB[j] = *(const s16x8*)&feat1[(size_t)(ssm[hw2 + 8][j]*32 + bt)*256 + c0];
    }
    // stage [W2;Wres2] -> bf16 LDS rows 0..7 (8 x 256, padded stride 272)
    {
      const int r = tid >> 5, c8 = (tid & 31) * 8;
      const float* sw = (r < 4) ? &W2[r*256 + c8] : &Wr2[(r-4)*256 + c8];
      float4 aa = *(const float4*)sw;
      float4 bb = *(const float4*)(sw + 4);
      s16x8 o;
      o[0]=(short)f2b(aa.x); o[1]=(short)f2b(aa.y); o[2]=(short)f2b(aa.z); o[3]=(short)f2b(aa.w);
      o[4]=(short)f2b(bb.x); o[5]=(short)f2b(bb.y); o[6]=(short)f2b(bb.z); o[7]=(short)f2b(bb.w);
      *(s16x8*)&Wcb[r][c8] = o;
    }
    if (tid < 128) {
      const int nl = tid >> 2, h = tid & 3;
      const int rn = (nBase + nl)*32 + bt;
      const float erv = er1[rn*4 + h];
      float e[8]; float mx = -1e30f;
      #pragma unroll
      for (int j = 0; j < 8; ++j) {
        float v = el1[(ssm[nl][j]*32 + bt)*4 + h] + erv;
        v = v >= 0.f ? v : NEGS * v;
        e[j] = v; mx = fmaxf(mx, v);
      }
      float den = 0.f;
      #pragma unroll
      for (int j = 0; j < 8; ++j) { e[j] = __expf(e[j] - mx); den += e[j]; }
      const float inv = 1.f / den;
      #pragma unroll
      for (int j = 0; j < 8; ++j) wsm[nl][j][h] = e[j] * inv;
    }
    __syncthreads();
    #pragma unroll
    for (int p2 = 0; p2 < 2; ++p2) {
      const int nlA = p2*16 + hw2, nlB = nlA + 8;
      if (p2 == 1) {
        #pragma unroll
        for (int j = 0; j < 8; ++j) {
          vA[j] = *(const s16x8*)&feat1[(size_t)(ssm[nlA][j]*32 + bt)*256 + c0];
          vB[j] = *(const s16x8*)&feat1[(size_t)(ssm[nlB][j]*32 + bt)*256 + c0];
        }
      }
      asm volatile("" ::: "memory");
      const s16x8 rrA = h1r[p2][0], rrB = h1r[p2][1];
      float aA[8] = {0,0,0,0,0,0,0,0}, aB[8] = {0,0,0,0,0,0,0,0};
      #pragma unroll
      for (int j = 0; j < 8; ++j) {
        const float wA = wsm[nlA][j][hh], wB = wsm[nlB][j][hh];
        #pragma unroll
        for (int i = 0; i < 8; ++i) {
          aA[i] = fmaf(wA, b2f((unsigned short)vA[j][i]), aA[i]);
          aB[i] = fmaf(wB, b2f((unsigned short)vB[j][i]), aB[i]);
        }
      }
      s16x8 oA, oB;
      #pragma unroll
      for (int i = 0; i < 8; ++i) {
        float xA = aA[i] + b2f((unsigned short)rrA[i]);
        float xB = aB[i] + b2f((unsigned short)rrB[i]);
        xA = xA > 0.f ? xA : elu_neg(xA);
        xB = xB > 0.f ? xB : elu_neg(xB);
        oA[i] = (short)f2b(xA); oB[i] = (short)f2b(xB);
      }
      *(s16x8*)&At2[nlA][c0] = oA;
      *(s16x8*)&At2[nlB][c0] = oB;
    }
    __syncthreads();
    // MFMA proj: h2[32x256] @ Wcat^T[8x256]. Waves 0/1 own row-tile rt = w.
    if (w < 2) {
      const int rt = w;
      f32x4 acc = (f32x4){0.f,0.f,0.f,0.f};
      #pragma unroll
      for (int kc = 0; kc < 8; ++kc) {
        s16x8 af = *(const s16x8*)&At2[rt*16 + n16][kc*32 + q*8];
        s16x8 bfr = (s16x8){0,0,0,0,0,0,0,0};
        if (n16 < 8) bfr = *(const s16x8*)&Wcb[n16][kc*32 + q*8];
        acc = __builtin_amdgcn_mfma_f32_16x16x32_bf16(af, bfr, acc, 0, 0, 0);
      }
      // C layout: col (output o) = n16, row (node) = rt*16 + q*4 + reg
      #pragma unroll
      for (int reg = 0; reg < 4; ++reg) {
        const int nl = rt*16 + q*4 + reg;
        const float v = acc[reg];
        if (n16 < 4) {
          feat2[((size_t)(nBase + nl)*32 + bt)*4 + n16] = v;   // global: gathered by peers
          f2_s[nl][n16] = v;                                   // LDS: self-use in A2a
        } else if (n16 < 8) {
          res_s[nl][n16 - 4] = v;                              // LDS only
        }
      }
    }
  }
  gbar(bar + (2*8 + g)*128, sub);

  // ------- Phase A2a: layer-2 aggregate + per-(b,t) tc1 partial -> x1 atomics -------
  if (tid < 128) {
    const int nl = tid >> 2, h = tid & 3;
    const int n = nBase + nl;
    const float av = al2[h], rv = ar2[h];
    const float erv = f2_s[nl][h] * rv;     // self feat2 from LDS
    float f[8], e[8]; float m = -1e30f;
    #pragma unroll
    for (int j = 0; j < 8; ++j) {
      f[j] = feat2[(ssm[nl][j]*32 + bt)*4 + h];
      float v = f[j]*av + erv;
      v = v >= 0.f ? v : NEGS * v;
      e[j] = v; m = fmaxf(m, v);
    }
    float den = 0.f, num = 0.f;
    #pragma unroll
    for (int j = 0; j < 8; ++j) { float ex = __expf(e[j]-m); den += ex; num = fmaf(ex, f[j], num); }
    const float os = num/den + res_s[nl][h];  // residual from LDS
    // partial einsum: x1[b][o][n] += tc1w[o][h][t] * os, summed over this 4-lane h-group
    float po[4];
    #pragma unroll
    for (int o = 0; o < 4; ++o) po[o] = tc1w[(o*4 + h)*8 + t] * os;
    #pragma unroll
    for (int off = 1; off < 4; off <<= 1)
      #pragma unroll
      for (int o = 0; o < 4; ++o) po[o] += __shfl_xor(po[o], off);
    float v = (h==0) ? po[0] : (h==1) ? po[1] : (h==2) ? po[2] : po[3];
    atomicAdd(&x1[(b*4 + h)*1024 + n], v);
  }
}

// ============ head: LN1 -> tc2 -> LN2 -> conv (x1 is only 64KB) ============
__global__ __launch_bounds__(256) void k_fin(
    const float* __restrict__ x1g, const float* __restrict__ tc1b,
    const float* __restrict__ ln1g, const float* __restrict__ ln1b,
    const float* __restrict__ tc2w, const float* __restrict__ tc2b,
    const float* __restrict__ ln2g, const float* __restrict__ ln2b,
    const float* __restrict__ fcw, const float* __restrict__ fcb,
    float* __restrict__ out)
{
  __shared__ __align__(16) float x1s[4][1024];
  __shared__ float x2s[1024];
  __shared__ float redA[4], redB[4];
  __shared__ float redC[4][7];
  const int bb = blockIdx.x, tid = threadIdx.x;
  const int wv = tid >> 6, lane = tid & 63;
  float s = 0.f, qq = 0.f;
  #pragma unroll
  for (int i = 0; i < 4; ++i) {
    const int n = tid + i*256;
    #pragma unroll
    for (int o = 0; o < 4; ++o) {
      float a = x1g[(bb*4 + o)*1024 + n] + tc1b[o];
      x1s[o][n] = a; s += a; qq += a*a;
    }
  }
  #pragma unroll
  for (int o = 32; o > 0; o >>= 1) { s += __shfl_down(s, o); qq += __shfl_down(qq, o); }
  if (lane == 0) { redA[wv] = s; redB[wv] = qq; }
  __syncthreads();
  const float S = redA[0]+redA[1]+redA[2]+redA[3];
  const float Q = redB[0]+redB[1]+redB[2]+redB[3];
  const float mu  = S * (1.f/4096.f);
  const float var = Q * (1.f/4096.f) - mu*mu;
  const float inv = rsqrtf(var + EPSF);
  const float tb = tc2b[0];
  const float r0 = tc2w[0], r1 = tc2w[1], r2 = tc2w[2], r3 = tc2w[3];
  float accv[4]; float s2 = 0.f, q2 = 0.f;
  #pragma unroll
  for (int i = 0; i < 4; ++i) {
    const int n = tid + i*256;
    float4 g4 = *(const float4*)&ln1g[n*4];
    float4 b4 = *(const float4*)&ln1b[n*4];
    float a = tb;
    a = fmaf(r0, (x1s[0][n]-mu)*inv*g4.x + b4.x, a);
    a = fmaf(r1, (x1s[1][n]-mu)*inv*g4.y + b4.y, a);
    a = fmaf(r2, (x1s[2][n]-mu)*inv*g4.z + b4.z, a);
    a = fmaf(r3, (x1s[3][n]-mu)*inv*g4.w + b4.w, a);
    accv[i] = a; s2 += a; q2 += a*a;
  }
  __syncthreads();   // before reusing redA/redB
  #pragma unroll
  for (int o = 32; o > 0; o >>= 1) { s2 += __shfl_down(s2, o); q2 += __shfl_down(q2, o); }
  if (lane == 0) { redA[wv] = s2; redB[wv] = q2; }
  __syncthreads();
  const float S2 = redA[0]+redA[1]+redA[2]+redA[3];
  const float Q2 = redB[0]+redB[1]+redB[2]+redB[3];
  const float mu2  = S2 * (1.f/1024.f);
  const float inv2 = rsqrtf(Q2 * (1.f/1024.f) - mu2*mu2 + EPSF);
  #pragma unroll
  for (int i = 0; i < 4; ++i) {
    const int n = tid + i*256;
    x2s[n] = (accv[i] - mu2) * inv2 * ln2g[n] + ln2b[n];
  }
  __syncthreads();
  float pc[7] = {0.f,0.f,0.f,0.f,0.f,0.f,0.f};
  for (int k = tid; k < 1018; k += 256) {
    const float fw = fcw[k];
    #pragma unroll
    for (int c = 0; c < 7; ++c) pc[c] = fmaf(x2s[k + c], fw, pc[c]);
  }
  #pragma unroll
  for (int o = 32; o > 0; o >>= 1)
    #pragma unroll
    for (int c = 0; c < 7; ++c) pc[c] += __shfl_down(pc[c], o);
  if (lane == 0) {
    #pragma unroll
    for (int c = 0; c < 7; ++c) redC[wv][c] = pc[c];
  }
  __syncthreads();
  if (tid < 7)
    out[bb*7 + tid] = redC[0][tid] + redC[1][tid] + redC[2][tid] + redC[3][tid] + fcb[0];
}

extern "C" void kernel_launch(void* const* d_in, const int* in_sizes, int n_in,
                              void* d_out, int out_size, void* d_ws, size_t ws_size,
                              hipStream_t stream)
{
  const float* inp  = (const float*)d_in[0];
  const int*   src  = (const int*)  d_in[1];
  const float* W0   = (const float*)d_in[3];
  const float* al0  = (const float*)d_in[4];
  const float* ar0  = (const float*)d_in[5];
  const float* W1   = (const float*)d_in[6];
  const float* al1  = (const float*)d_in[7];
  const float* ar1  = (const float*)d_in[8];
  const float* W2   = (const float*)d_in[9];
  const float* al2  = (const float*)d_in[10];
  const float* ar2  = (const float*)d_in[11];
  const float* Wr2  = (const float*)d_in[12];
  const float* tc1w = (const float*)d_in[13];
  const float* tc1b = (const float*)d_in[14];
  const float* ln1g = (const float*)d_in[15];
  const float* ln1b = (const float*)d_in[16];
  const float* tc2w = (const float*)d_in[17];
  const float* tc2b = (const float*)d_in[18];
  const float* ln2g = (const float*)d_in[19];
  const float* ln2b = (const float*)d_in[20];
  const float* fcw  = (const float*)d_in[21];
  const float* fcb  = (const float*)d_in[22];
  float* out = (float*)d_out;

  unsigned short* W1bX   = (unsigned short*)d_ws;    // 8 XCD copies: 524,288 shorts
  unsigned short* featb0 = W1bX   + 524288;          // 8,388,608
  unsigned short* featb1 = featb0 + 8388608;         // 8,388,608
  float* el0   = (float*)(featb1 + 8388608);         // 131,072 each
  float* er0   = el0   + 131072;
  float* el1   = er0   + 131072;
  float* er1   = el1   + 131072;
  float* feat2 = er1   + 131072;
  float* x1    = feat2 + 131072;                     // 16,384 floats (64 KB)
  int*   bar   = (int*)(x1 + 16384);                 // 3 phases x 8 groups x 512B

  // zero x1 accumulator (64KB) + barrier state (12KB) in one memset
  hipMemsetAsync(x1, 0, 16384*4 + 12288, stream);
  k_mega<<<dim3(1024), dim3(256), 0, stream>>>(inp, src, W0, al0, ar0, W1, al1, ar1,
                                               W2, al2, ar2, Wr2, tc1w,
                                               W1bX, featb0, featb1,
                                               el0, er0, el1, er1, feat2, x1, bar);
  k_fin<<<dim3(4), dim3(256), 0, stream>>>(x1, tc1b, ln1g, ln1b, tc2w, tc2b,
                                           ln2g, ln2b, fcw, fcb, out);
}